// Round 5
// baseline (10502.184 us; speedup 1.0000x reference)
//
#include <hip/hip_runtime.h>
#include <math.h>

#define NV      50000
#define T_STEPS 1023
#define KDIM    1024
#define NCH     782   // ceil(50000/64)
typedef unsigned long long ull;

// ws layout (bytes):
//   [0, 8192)            (unused)
//   [8192, 12288)        Psum  f32[1024]
//   [12288, 16384)       Ttgt  f32[1024]
//   [16384, 24576)       Hm1   f64[1024]   (h_{-1} = z upcast)
//   [24K, 24K+4M)        X     f32[1024*1024]
//   [24K+4M, 24K+28M)    GI    f64[1024*3072]; after recurrence:
//                          [+0, +8M)       E f64[1024*1024]
//                          [+8M, +14.5M)   candL f32[1024*1564]
//                          [+14.5M,+21M)   candI i32[1024*1564]
//   [24K+28M, 24K+36M)   H     f64[1024*1024]
// total ~36.02 MiB

// ---------------------------------------------------------------- gather ----
__global__ __launch_bounds__(256) void k_gather(const int* __restrict__ inputs,
                                                const float* __restrict__ emb,
                                                float* __restrict__ X) {
  const int t = blockIdx.x;      // 0..1023 (row 1023 = zero pad)
  const int tid = threadIdx.x;
  float4 v = make_float4(0.f, 0.f, 0.f, 0.f);
  if (t < T_STEPS) {
    const int tok = (t == 0) ? 0 : inputs[t];
    v = *(const float4*)&emb[(size_t)tok * KDIM + tid * 4];
  }
  *(float4*)&X[(size_t)t * KDIM + tid * 4] = v;
}

// ------------------------------------------------------------- z upcast -----
__global__ __launch_bounds__(256) void k_initz(const float* __restrict__ z,
                                               double* __restrict__ Hm1) {
  const int i = blockIdx.x * 256 + threadIdx.x;
  Hm1[i] = (double)z[i];
}

// ---------------- NT GEMM: A f32 x B f32 -> C f64, fp64 accumulate ----------
__global__ __launch_bounds__(256) void k_gemm_ffd(const float* __restrict__ A,
                                                  const float* __restrict__ B,
                                                  const float* __restrict__ bias,
                                                  double* __restrict__ C,
                                                  int N, int K) {
  __shared__ float As[32][68];
  __shared__ float Bs[32][68];
  const int tid = threadIdx.x;
  const int bx = blockIdx.x, by = blockIdx.y;
  const int lr = tid >> 2;            // 0..63
  const int lk = (tid & 3) * 8;       // 0,8,16,24
  const float* Ap = A + (size_t)(by * 64 + lr) * K + lk;
  const float* Bp = B + (size_t)(bx * 64 + lr) * K + lk;
  const int r0 = (tid >> 4) * 4;
  const int c0 = (tid & 15) * 4;
  double acc[4][4] = {};
  for (int kc = 0; kc < K; kc += 32) {
    const float4 a0 = *(const float4*)(Ap + kc);
    const float4 a1 = *(const float4*)(Ap + kc + 4);
    const float4 b0 = *(const float4*)(Bp + kc);
    const float4 b1 = *(const float4*)(Bp + kc + 4);
    __syncthreads();
    As[lk+0][lr]=a0.x; As[lk+1][lr]=a0.y; As[lk+2][lr]=a0.z; As[lk+3][lr]=a0.w;
    As[lk+4][lr]=a1.x; As[lk+5][lr]=a1.y; As[lk+6][lr]=a1.z; As[lk+7][lr]=a1.w;
    Bs[lk+0][lr]=b0.x; Bs[lk+1][lr]=b0.y; Bs[lk+2][lr]=b0.z; Bs[lk+3][lr]=b0.w;
    Bs[lk+4][lr]=b1.x; Bs[lk+5][lr]=b1.y; Bs[lk+6][lr]=b1.z; Bs[lk+7][lr]=b1.w;
    __syncthreads();
#pragma unroll
    for (int kk = 0; kk < 32; ++kk) {
      const float4 av = *(const float4*)&As[kk][r0];
      const float4 bv = *(const float4*)&Bs[kk][c0];
      const double aa[4] = {av.x, av.y, av.z, av.w};
      const double bb[4] = {bv.x, bv.y, bv.z, bv.w};
#pragma unroll
      for (int i = 0; i < 4; ++i)
#pragma unroll
        for (int j = 0; j < 4; ++j)
          acc[i][j] = fma(aa[i], bb[j], acc[i][j]);
    }
  }
  const int row = by * 64 + r0;
  const int col = bx * 64 + c0;
#pragma unroll
  for (int i = 0; i < 4; ++i)
#pragma unroll
    for (int j = 0; j < 4; ++j)
      C[(size_t)(row + i) * N + col + j] = acc[i][j] + (double)bias[col + j];
}

// ---------------- NT GEMM: A f64 x B f32 -> C f64, fp64 accumulate ----------
__global__ __launch_bounds__(256) void k_gemm_dfd(const double* __restrict__ A,
                                                  const float* __restrict__ B,
                                                  const float* __restrict__ bias,
                                                  double* __restrict__ C,
                                                  int N, int K) {
  __shared__ double As[32][68];
  __shared__ float  Bs[32][68];
  const int tid = threadIdx.x;
  const int bx = blockIdx.x, by = blockIdx.y;
  const int lr = tid >> 2;
  const int lk = (tid & 3) * 8;
  const double* Ap = A + (size_t)(by * 64 + lr) * K + lk;
  const float*  Bp = B + (size_t)(bx * 64 + lr) * K + lk;
  const int r0 = (tid >> 4) * 4;
  const int c0 = (tid & 15) * 4;
  double acc[4][4] = {};
  for (int kc = 0; kc < K; kc += 32) {
    double ar[8];
#pragma unroll
    for (int q = 0; q < 8; ++q) ar[q] = Ap[kc + q];
    const float4 b0 = *(const float4*)(Bp + kc);
    const float4 b1 = *(const float4*)(Bp + kc + 4);
    __syncthreads();
#pragma unroll
    for (int q = 0; q < 8; ++q) As[lk + q][lr] = ar[q];
    Bs[lk+0][lr]=b0.x; Bs[lk+1][lr]=b0.y; Bs[lk+2][lr]=b0.z; Bs[lk+3][lr]=b0.w;
    Bs[lk+4][lr]=b1.x; Bs[lk+5][lr]=b1.y; Bs[lk+6][lr]=b1.z; Bs[lk+7][lr]=b1.w;
    __syncthreads();
#pragma unroll
    for (int kk = 0; kk < 32; ++kk) {
      const double aa[4] = {As[kk][r0+0], As[kk][r0+1], As[kk][r0+2], As[kk][r0+3]};
      const float4 bv = *(const float4*)&Bs[kk][c0];
      const double bb[4] = {bv.x, bv.y, bv.z, bv.w};
#pragma unroll
      for (int i = 0; i < 4; ++i)
#pragma unroll
        for (int j = 0; j < 4; ++j)
          acc[i][j] = fma(aa[i], bb[j], acc[i][j]);
    }
  }
  const int row = by * 64 + r0;
  const int col = bx * 64 + c0;
#pragma unroll
  for (int i = 0; i < 4; ++i)
#pragma unroll
    for (int j = 0; j < 4; ++j)
      C[(size_t)(row + i) * N + col + j] = acc[i][j] + (double)bias[col + j];
}

// ------------------- one GRU step = one kernel launch -----------------------
__global__ __launch_bounds__(512) void k_step(const float* __restrict__ Whh,
                                              const float* __restrict__ bhh,
                                              const double* __restrict__ gi_row,
                                              const double* __restrict__ h_prev,
                                              double* __restrict__ h_out) {
  __shared__ double hs[1024];
  const int tid = threadIdx.x;
  const int w = tid >> 6, l = tid & 63;
  const int i = blockIdx.x * 8 + w;
  hs[tid]       = h_prev[tid];
  hs[tid + 512] = h_prev[tid + 512];
  __syncthreads();
  const float* w_r = Whh + (size_t)i * 1024;
  const float* w_z = Whh + (size_t)(1024 + i) * 1024;
  const float* w_n = Whh + (size_t)(2048 + i) * 1024;
  double sr = 0.0, sz = 0.0, sn = 0.0;
#pragma unroll 4
  for (int m = 0; m < 16; ++m) {
    const int k = l + 64 * m;
    const double hv = hs[k];
    sr = fma((double)w_r[k], hv, sr);
    sz = fma((double)w_z[k], hv, sz);
    sn = fma((double)w_n[k], hv, sn);
  }
#pragma unroll
  for (int mk = 32; mk >= 1; mk >>= 1) {
    sr += __shfl_xor(sr, mk, 64);
    sz += __shfl_xor(sz, mk, 64);
    sn += __shfl_xor(sn, mk, 64);
  }
  if (l == 0) {
    const double r  = 1.0 / (1.0 + exp(-(gi_row[i]        + sr + (double)bhh[i])));
    const double zg = 1.0 / (1.0 + exp(-(gi_row[1024 + i] + sz + (double)bhh[1024 + i])));
    const double n  = tanh(gi_row[2048 + i] + r * (sn + (double)bhh[2048 + i]));
    h_out[i] = (1.0 - zg) * n + zg * hs[i];
  }
}

// ------- logits GEMM (f64) + per-chunk fp32 top-2 candidates + loss stats ---
__global__ __launch_bounds__(256) void k_logits(const double* __restrict__ E,
                                                const float* __restrict__ emb,
                                                const float* __restrict__ out_b,
                                                const int* __restrict__ inputs,
                                                float* __restrict__ candL,
                                                int* __restrict__ candI,
                                                float* __restrict__ Psum,
                                                float* __restrict__ Ttgt) {
  __shared__ double As[32][68];
  __shared__ float  Bs[32][68];
  const int tid = threadIdx.x;
  const int bx = blockIdx.x, by = blockIdx.y;
  const int lr = tid >> 2;
  const int lk = (tid & 3) * 8;
  const int brow = bx * 64 + lr;
  const double* Ap = E + (size_t)(by * 64 + lr) * KDIM + lk;
  const float*  Bp = emb + (size_t)brow * KDIM + lk;
  const bool bvalid = (brow < NV);
  const int r0 = (tid >> 4) * 4;
  const int c0 = (tid & 15) * 4;
  double acc[4][4] = {};
  for (int kc = 0; kc < KDIM; kc += 32) {
    double ar[8];
#pragma unroll
    for (int q = 0; q < 8; ++q) ar[q] = Ap[kc + q];
    float4 b0 = make_float4(0.f, 0.f, 0.f, 0.f);
    float4 b1 = make_float4(0.f, 0.f, 0.f, 0.f);
    if (bvalid) { b0 = *(const float4*)(Bp + kc); b1 = *(const float4*)(Bp + kc + 4); }
    __syncthreads();
#pragma unroll
    for (int q = 0; q < 8; ++q) As[lk + q][lr] = ar[q];
    Bs[lk+0][lr]=b0.x; Bs[lk+1][lr]=b0.y; Bs[lk+2][lr]=b0.z; Bs[lk+3][lr]=b0.w;
    Bs[lk+4][lr]=b1.x; Bs[lk+5][lr]=b1.y; Bs[lk+6][lr]=b1.z; Bs[lk+7][lr]=b1.w;
    __syncthreads();
#pragma unroll
    for (int kk = 0; kk < 32; ++kk) {
      const double aa[4] = {As[kk][r0+0], As[kk][r0+1], As[kk][r0+2], As[kk][r0+3]};
      const float4 bv = *(const float4*)&Bs[kk][c0];
      const double bb[4] = {bv.x, bv.y, bv.z, bv.w};
#pragma unroll
      for (int i = 0; i < 4; ++i)
#pragma unroll
        for (int j = 0; j < 4; ++j)
          acc[i][j] = fma(aa[i], bb[j], acc[i][j]);
    }
  }
  const int colb = bx * 64 + c0;
#pragma unroll
  for (int i = 0; i < 4; ++i) {
    const int s = by * 64 + r0 + i;
    const bool valid = (s < T_STEPS);
    const int tgt = valid ? inputs[s + 1] : -1;
    float L1 = -3e38f, L2 = -3e38f;
    int   i1 = 0x7FFFFFFF, i2 = 0x7FFFFFFF;
    float se = 0.f, tv = -INFINITY;
#pragma unroll
    for (int j = 0; j < 4; ++j) {
      const int v = colb + j;
      if (v < NV) {
        const double lgd = acc[i][j] + (double)out_b[v];
        const float L = (float)lgd;           // np's fp32 logit (bit-matched)
        se += expf((float)(lgd - 0.01));
        if (v == tgt) tv = (float)lgd;
        if (L > L1 || (L == L1 && v < i1)) { L2 = L1; i2 = i1; L1 = L; i1 = v; }
        else if (L > L2 || (L == L2 && v < i2)) { L2 = L; i2 = v; }
      }
    }
#pragma unroll
    for (int mk = 1; mk <= 8; mk <<= 1) {
      const float oL1 = __shfl_xor(L1, mk, 64); const int oi1 = __shfl_xor(i1, mk, 64);
      const float oL2 = __shfl_xor(L2, mk, 64); const int oi2 = __shfl_xor(i2, mk, 64);
      if (oL1 > L1 || (oL1 == L1 && oi1 < i1)) { L2 = L1; i2 = i1; L1 = oL1; i1 = oi1; }
      else if (oL1 > L2 || (oL1 == L2 && oi1 < i2)) { L2 = oL1; i2 = oi1; }
      if (oL2 > L1 || (oL2 == L1 && oi2 < i1)) { L2 = L1; i2 = i1; L1 = oL2; i1 = oi2; }
      else if (oL2 > L2 || (oL2 == L2 && oi2 < i2)) { L2 = oL2; i2 = oi2; }
      se += __shfl_xor(se, mk, 64);
      tv = fmaxf(tv, __shfl_xor(tv, mk, 64));
    }
    if (((tid & 15) == 0) && valid) {
      const size_t p = (size_t)s * (2 * NCH) + 2 * bx;
      candL[p] = L1;     candI[p] = i1;
      candL[p + 1] = L2; candI[p + 1] = i2;
      atomicAdd(&Psum[s], se);
      if (tv > -1e30f) Ttgt[s] = tv;
    }
  }
}

// --------- preds: np-faithful fp32 log_softmax quantized argmax -------------
// q_v = fl32(fl32(L_v - Lmax) - 10.8125f); ties -> lowest index.
// Anchor invariance: any fp32 S in [8,16) differs from np's S by an exact
// integer multiple of ulp -> identical tie partition.
__global__ __launch_bounds__(256) void k_preds(const float* __restrict__ candL,
                                               const int* __restrict__ candI,
                                               float* __restrict__ out) {
  __shared__ float sL[256];
  __shared__ int   sI[256];
  const int s = blockIdx.x;        // 0..1022
  const int tid = threadIdx.x;
  const int n = 2 * NCH;           // 1564
  const size_t base = (size_t)s * n;
  float m = -3e38f;
  for (int c = tid; c < n; c += 256) m = fmaxf(m, candL[base + c]);
  sL[tid] = m; __syncthreads();
  for (int st = 128; st > 0; st >>= 1) {
    if (tid < st) sL[tid] = fmaxf(sL[tid], sL[tid + st]);
    __syncthreads();
  }
  const float Lmax = sL[0];
  __syncthreads();
  float bq = -3e38f; int bi = 0x7FFFFFFF;
  for (int c = tid; c < n; c += 256) {
    const float L = candL[base + c];
    const int   v = candI[base + c];
    const float d = L - Lmax;              // Sterbenz-exact
    const float q = d - 10.8125f;          // fp32 bucket quantization
    if (q > bq || (q == bq && v < bi)) { bq = q; bi = v; }
  }
  sL[tid] = bq; sI[tid] = bi; __syncthreads();
  for (int st = 128; st > 0; st >>= 1) {
    if (tid < st) {
      if (sL[tid + st] > sL[tid] ||
          (sL[tid + st] == sL[tid] && sI[tid + st] < sI[tid])) {
        sL[tid] = sL[tid + st]; sI[tid] = sI[tid + st];
      }
    }
    __syncthreads();
  }
  if (tid == 0) out[2 + s] = (float)sI[0];
}

// ------------------------------------------------ final loss ----------------
__global__ __launch_bounds__(1024) void k_finish(const float* __restrict__ Psum,
                                                 const float* __restrict__ Ttgt,
                                                 float* __restrict__ out) {
  __shared__ double red[1024];
  const int s = threadIdx.x;
  double ls = 0.0;
  if (s < T_STEPS) ls = 0.01 + log((double)Psum[s]) - (double)Ttgt[s];
  red[s] = ls;
  __syncthreads();
  for (int st = 512; st > 0; st >>= 1) {
    if (s < st) red[s] += red[s + st];
    __syncthreads();
  }
  if (s == 0) out[0] = (float)red[0];
  if (s == 1) out[1] = 0.f;
}

// ----------------------------------------------------------------- launch ---
extern "C" void kernel_launch(void* const* d_in, const int* in_sizes, int n_in,
                              void* d_out, int out_size, void* d_ws, size_t ws_size,
                              hipStream_t stream) {
  const int*   inputs = (const int*)  d_in[0];
  const float* z      = (const float*)d_in[1];
  const float* emb    = (const float*)d_in[2];
  const float* out_b  = (const float*)d_in[3];
  const float* h2eW   = (const float*)d_in[4];
  const float* h2eb   = (const float*)d_in[5];
  const float* Wih    = (const float*)d_in[6];
  const float* Whh    = (const float*)d_in[7];
  const float* bih    = (const float*)d_in[8];
  const float* bhh    = (const float*)d_in[9];

  char* ws8 = (char*)d_ws;
  float*  Psum = (float*)(ws8 + 8192);                   // 4 KiB
  float*  Ttgt = (float*)(ws8 + 12288);                  // 4 KiB
  double* Hm1  = (double*)(ws8 + 16384);                 // 8 KiB
  float*  X    = (float*)(ws8 + 24576);                  // 4 MiB
  char*   GIb  = ws8 + 24576 + (4u << 20);               // 24 MiB region
  double* GI   = (double*)GIb;
  double* E    = GI;                                     // 8 MiB overlay
  float*  candL = (float*)(GIb + (8u << 20));            // 6.11 MiB
  int*    candI = (int*)  (GIb + (8u << 20) + 6815744);  // 6.11 MiB
  double* H    = (double*)(ws8 + 24576 + (28u << 20));   // 8 MiB
  float*  out  = (float*)d_out;

  hipMemsetAsync(ws8, 0, 16384, stream);                 // Psum etc.

  k_gather<<<1024, 256, 0, stream>>>(inputs, emb, X);
  k_initz<<<4, 256, 0, stream>>>(z, Hm1);
  k_gemm_ffd<<<dim3(48, 16), 256, 0, stream>>>(X, Wih, bih, GI, 3072, KDIM);

  for (int t = 0; t < T_STEPS; ++t) {
    const double* hp = (t == 0) ? Hm1 : (H + (size_t)(t - 1) * KDIM);
    k_step<<<128, 512, 0, stream>>>(Whh, bhh, GI + (size_t)t * 3072,
                                    hp, H + (size_t)t * KDIM);
  }

  k_gemm_dfd<<<dim3(16, 16), 256, 0, stream>>>(H, h2eW, h2eb, E, KDIM, KDIM);
  k_logits<<<dim3(NCH, 16), 256, 0, stream>>>(E, emb, out_b, inputs,
                                              candL, candI, Psum, Ttgt);
  k_preds<<<T_STEPS, 256, 0, stream>>>(candL, candI, out);
  k_finish<<<1, 1024, 0, stream>>>(Psum, Ttgt, out);
}